// Round 4
// baseline (266.386 us; speedup 1.0000x reference)
//
#include <hip/hip_runtime.h>
#include <hip/hip_bf16.h>
#include <math.h>

#define B_   16
#define LQ_  2048
#define LK_  2048
#define D_   128
#define LN_EPS 1e-5f
#define NTILE (LK_ / 64)

typedef __attribute__((ext_vector_type(8))) short short8;
typedef __attribute__((ext_vector_type(4))) float f32x4;

union FragU { uint4 u4; short8 s8; unsigned int u[4]; };

__device__ __forceinline__ unsigned int pk_bf16(float a, float b) {
  __hip_bfloat162 h = __float22bfloat162_rn(make_float2(a, b));
  unsigned int u;
  __builtin_memcpy(&u, &h, 4);
  return u;
}
__device__ __forceinline__ float bf_lo(unsigned int u){ unsigned int v = u << 16; float f; __builtin_memcpy(&f, &v, 4); return f; }
__device__ __forceinline__ float bf_hi(unsigned int u){ unsigned int v = u & 0xffff0000u; float f; __builtin_memcpy(&f, &v, 4); return f; }
__device__ __forceinline__ unsigned short bf16_bits(float x) {
  return (unsigned short)(pk_bf16(x, 0.f) & 0xffffu);
}

// K tiles: ushort [64 rows][128 d], 16B(8-ushort)-chunk XOR swizzle by row.
__device__ __forceinline__ int idxK(int row, int d) {
  return row * 128 + ((((d >> 3) ^ row) & 15) << 3) + (d & 7);
}
// Vt: uint words [128 d][32 kv-pairs]; 16B(4-word)-chunk swizzle by h(d).
// h mixes d[4:2] with d[1:0] so both writer lanes (d=4*lane+j) and reader
// lanes (d=n*16+lr) spread across chunks.
__device__ __forceinline__ int idxVt(int d, int kp) {
  int h = ((d >> 2) ^ ((d & 3) << 1)) & 7;
  return d * 32 + ((((kp >> 2) ^ h) & 7) << 2) + (kp & 3);
}
// Ps: ushort [2 waves][32 rows][64 cols], 8-ushort-chunk swizzle by row.
__device__ __forceinline__ int idxPs(int w, int row, int col) {
  return (w * 32 + row) * 64 + ((((col >> 3) ^ row) & 7) << 3) + (col & 7);
}

// LDS-only barrier: drains ds ops, leaves global (vmcnt) loads in flight.
__device__ __forceinline__ void barrier_lds() {
  asm volatile("s_waitcnt lgkmcnt(0)\n\ts_barrier" ::: "memory");
}

__global__ __launch_bounds__(128, 1) void attn_ln_mfma(
    const float* __restrict__ qg, const float* __restrict__ kg,
    const float* __restrict__ vg, const float* __restrict__ maskg,
    const float* __restrict__ gammag, const float* __restrict__ betag,
    float* __restrict__ outg)
{
  __shared__ unsigned short KhS[64 * 128];   // 16 KB
  __shared__ unsigned short KlS[64 * 128];   // 16 KB
  __shared__ unsigned int   VtW[128 * 32];   // 16 KB (bf16 pairs)
  __shared__ unsigned short PsS[2 * 32 * 64];// 8 KB
  // total 56 KB -> 2 blocks/CU

  const int tid  = threadIdx.x;
  const int w    = tid >> 6;        // wave 0..1
  const int lane = tid & 63;
  const int quad = lane >> 4;
  const int lr   = lane & 15;

  // XCD swizzle: blocks on XCD x serve batches {2x, 2x+1} -> K/V fits L2.
  const int id   = blockIdx.x;
  const int xcd  = id & 7;
  const int slot = id >> 3;
  const int b    = xcd * 2 + (slot >> 5);
  const int q0   = (slot & 31) * 64;

  // staging thread mapping
  const int c8  = tid & 15;         // K: 8-d chunk, d0 = c8*8
  const int kr0 = tid >> 4;         // K: rows kr0 + 8i
  const int vc  = tid & 31;         // V: d0 = vc*4
  const int vr  = tid >> 5;         // V: kv-pairs vr + 4j

  const float* gkbase = kg + ((size_t)b * LK_) * D_;
  const float* gvbase = vg + ((size_t)b * LK_) * D_;

  // ---- prefetch tile 0 K into registers ----
  float4 kpre[8][2];
#pragma unroll
  for (int i = 0; i < 8; i++) {
    const float* p = gkbase + (size_t)(kr0 + 8 * i) * D_ + c8 * 8;
    kpre[i][0] = *(const float4*)(p);
    kpre[i][1] = *(const float4*)(p + 4);
  }

  // ---- Q fragments (hi/lo) for 2 row-tiles, registers for whole k-loop ----
  short8 qh[2][4], ql[2][4];
#pragma unroll
  for (int rt = 0; rt < 2; rt++) {
    const float* qrow = qg + ((size_t)b * LQ_ + q0 + w * 32 + rt * 16 + lr) * D_ + quad * 8;
#pragma unroll
    for (int c = 0; c < 4; c++) {
      float4 x = *(const float4*)(qrow + c * 32);
      float4 y = *(const float4*)(qrow + c * 32 + 4);
      FragU H, L;
      H.u[0] = pk_bf16(x.x, x.y); H.u[1] = pk_bf16(x.z, x.w);
      H.u[2] = pk_bf16(y.x, y.y); H.u[3] = pk_bf16(y.z, y.w);
      L.u[0] = pk_bf16(x.x - bf_lo(H.u[0]), x.y - bf_hi(H.u[0]));
      L.u[1] = pk_bf16(x.z - bf_lo(H.u[1]), x.w - bf_hi(H.u[1]));
      L.u[2] = pk_bf16(y.x - bf_lo(H.u[2]), y.y - bf_hi(H.u[2]));
      L.u[3] = pk_bf16(y.z - bf_lo(H.u[3]), y.w - bf_hi(H.u[3]));
      qh[rt][c] = H.s8; ql[rt][c] = L.s8;
    }
  }

  float l_part[2][4];
  f32x4 o[2][8];
  const f32x4 zf = {0.f, 0.f, 0.f, 0.f};
#pragma unroll
  for (int rt = 0; rt < 2; rt++) {
#pragma unroll
    for (int r = 0; r < 4; r++) l_part[rt][r] = 0.f;
#pragma unroll
    for (int n = 0; n < 8; n++) o[rt][n] = zf;
  }

  for (int kt = 0; kt < NTILE; kt++) {
    const int k0 = kt * 64;
    barrier_lds();   // both waves fully done with previous tile

    // ---- stage K (hi/lo bf16) from prefetched registers, b128 writes ----
#pragma unroll
    for (int i = 0; i < 8; i++) {
      const int row = kr0 + 8 * i;
      float4 x = kpre[i][0], y = kpre[i][1];
      FragU H, L;
      H.u[0] = pk_bf16(x.x, x.y); H.u[1] = pk_bf16(x.z, x.w);
      H.u[2] = pk_bf16(y.x, y.y); H.u[3] = pk_bf16(y.z, y.w);
      L.u[0] = pk_bf16(x.x - bf_lo(H.u[0]), x.y - bf_hi(H.u[0]));
      L.u[1] = pk_bf16(x.z - bf_lo(H.u[1]), x.w - bf_hi(H.u[1]));
      L.u[2] = pk_bf16(y.x - bf_lo(H.u[2]), y.y - bf_hi(H.u[2]));
      L.u[3] = pk_bf16(y.z - bf_lo(H.u[3]), y.w - bf_hi(H.u[3]));
      const int ik = idxK(row, c8 * 8);
      *(uint4*)&KhS[ik] = H.u4;
      *(uint4*)&KlS[ik] = L.u4;
    }

    // ---- mask loads for this tile (consumed in softmax) ----
    float mkv[2][4][4];
#pragma unroll
    for (int rt = 0; rt < 2; rt++)
#pragma unroll
      for (int t = 0; t < 4; t++)
#pragma unroll
        for (int reg = 0; reg < 4; reg++)
          mkv[rt][t][reg] = maskg[(size_t)(q0 + w * 32 + rt * 16 + quad * 4 + reg) * LK_
                                  + k0 + t * 16 + lr];

    // ---- V loads for this tile (row pairs; land during QK phase) ----
    float4 va[8], vb[8];
#pragma unroll
    for (int j = 0; j < 8; j++) {
      const int kp = vr + 4 * j;
      va[j] = *(const float4*)(gvbase + (size_t)(k0 + 2 * kp) * D_ + vc * 4);
      vb[j] = *(const float4*)(gvbase + (size_t)(k0 + 2 * kp + 1) * D_ + vc * 4);
    }

    // ---- prefetch NEXT tile K (used after next top barrier) ----
    if (kt + 1 < NTILE) {
#pragma unroll
      for (int i = 0; i < 8; i++) {
        const float* p = gkbase + (size_t)(k0 + 64 + kr0 + 8 * i) * D_ + c8 * 8;
        kpre[i][0] = *(const float4*)(p);
        kpre[i][1] = *(const float4*)(p + 4);
      }
    }

    barrier_lds();   // K tile visible

    // ---- S = Q K^T via MFMA (hi/lo), 2 row-tiles share each K frag ----
    f32x4 sacc[2][4];
#pragma unroll
    for (int rt = 0; rt < 2; rt++)
#pragma unroll
      for (int t = 0; t < 4; t++) sacc[rt][t] = zf;
#pragma unroll
    for (int c = 0; c < 4; c++) {
      const int kb = c * 32 + quad * 8;
#pragma unroll
      for (int t = 0; t < 4; t++) {
        FragU kh, kl;
        kh.u4 = *(const uint4*)&KhS[idxK(t * 16 + lr, kb)];
        kl.u4 = *(const uint4*)&KlS[idxK(t * 16 + lr, kb)];
#pragma unroll
        for (int rt = 0; rt < 2; rt++) {
          sacc[rt][t] = __builtin_amdgcn_mfma_f32_16x16x32_bf16(qh[rt][c], kh.s8, sacc[rt][t], 0, 0, 0);
          sacc[rt][t] = __builtin_amdgcn_mfma_f32_16x16x32_bf16(ql[rt][c], kh.s8, sacc[rt][t], 0, 0, 0);
          sacc[rt][t] = __builtin_amdgcn_mfma_f32_16x16x32_bf16(qh[rt][c], kl.s8, sacc[rt][t], 0, 0, 0);
        }
      }
    }

    // ---- max-free softmax; P -> LDS as bf16 ----
#pragma unroll
    for (int rt = 0; rt < 2; rt++)
#pragma unroll
      for (int reg = 0; reg < 4; reg++) {
        float p[4];
#pragma unroll
        for (int t = 0; t < 4; t++) p[t] = __expf(sacc[rt][t][reg] + mkv[rt][t][reg]);
        l_part[rt][reg] += (p[0] + p[1]) + (p[2] + p[3]);
        const int prow = rt * 16 + quad * 4 + reg;
#pragma unroll
        for (int t = 0; t < 4; t++)
          PsS[idxPs(w, prow, t * 16 + lr)] = bf16_bits(p[t]);
      }

    // ---- convert + write V^T as bf16 kv-pairs (b32 writes) ----
#pragma unroll
    for (int j = 0; j < 8; j++) {
      const int kp = vr + 4 * j;
      float4 a = va[j], bb = vb[j];
      VtW[idxVt(vc * 4 + 0, kp)] = pk_bf16(a.x, bb.x);
      VtW[idxVt(vc * 4 + 1, kp)] = pk_bf16(a.y, bb.y);
      VtW[idxVt(vc * 4 + 2, kp)] = pk_bf16(a.z, bb.z);
      VtW[idxVt(vc * 4 + 3, kp)] = pk_bf16(a.w, bb.w);
    }

    barrier_lds();   // V tile + own Ps visible

    // ---- O += P * V via MFMA; V frag shared across row-tiles ----
#pragma unroll
    for (int s = 0; s < 2; s++) {
      FragU pa0, pa1;
      pa0.u4 = *(const uint4*)&PsS[idxPs(w, lr,      (s * 4 + quad) * 8)];
      pa1.u4 = *(const uint4*)&PsS[idxPs(w, 16 + lr, (s * 4 + quad) * 8)];
#pragma unroll
      for (int n = 0; n < 8; n++) {
        FragU Bv;
        Bv.u4 = *(const uint4*)&VtW[idxVt(n * 16 + lr, s * 16 + quad * 4)];
        o[0][n] = __builtin_amdgcn_mfma_f32_16x16x32_bf16(pa0.s8, Bv.s8, o[0][n], 0, 0, 0);
        o[1][n] = __builtin_amdgcn_mfma_f32_16x16x32_bf16(pa1.s8, Bv.s8, o[1][n], 0, 0, 0);
      }
    }
  }

  // ---- epilogue: reduce l, normalize, LayerNorm, store ----
  float gam[8], bet[8];
#pragma unroll
  for (int n = 0; n < 8; n++) {
    gam[n] = gammag[n * 16 + lr];
    bet[n] = betag[n * 16 + lr];
  }

#pragma unroll
  for (int rt = 0; rt < 2; rt++)
#pragma unroll
    for (int reg = 0; reg < 4; reg++) {
      float l = l_part[rt][reg];
#pragma unroll
      for (int m = 1; m <= 8; m <<= 1) l += __shfl_xor(l, m, 64);
      const float inv_l = 1.f / l;

      float vals[8];
      float s1 = 0.f, s2 = 0.f;
#pragma unroll
      for (int n = 0; n < 8; n++) {
        vals[n] = o[rt][n][reg] * inv_l;
        s1 += vals[n]; s2 += vals[n] * vals[n];
      }
#pragma unroll
      for (int m = 1; m <= 8; m <<= 1) {
        s1 += __shfl_xor(s1, m, 64);
        s2 += __shfl_xor(s2, m, 64);
      }
      const float mean = s1 * (1.f / 128.f);
      const float var  = s2 * (1.f / 128.f) - mean * mean;
      const float rstd = rsqrtf(var + LN_EPS);

      float* op = outg + ((size_t)b * LQ_ + q0 + w * 32 + rt * 16 + quad * 4 + reg) * D_ + lr;
#pragma unroll
      for (int n = 0; n < 8; n++)
        op[n * 16] = (vals[n] - mean) * rstd * gam[n] + bet[n];
    }
}

extern "C" void kernel_launch(void* const* d_in, const int* in_sizes, int n_in,
                              void* d_out, int out_size, void* d_ws, size_t ws_size,
                              hipStream_t stream) {
  const float* q     = (const float*)d_in[0];
  const float* k     = (const float*)d_in[1];
  const float* v     = (const float*)d_in[2];
  const float* mask  = (const float*)d_in[3];
  const float* gamma = (const float*)d_in[4];
  const float* beta  = (const float*)d_in[5];
  float* out = (float*)d_out;

  attn_ln_mfma<<<dim3(512), dim3(128), 0, stream>>>(q, k, v, mask, gamma, beta, out);
}